// Round 1
// baseline (477.980 us; speedup 1.0000x reference)
//
#include <hip/hip_runtime.h>
#include <hip/hip_bf16.h>

// ---------------------------------------------------------------------------
// 2-layer GAT (PyG GATConv semantics, concat=False -> head mean, self-loops)
// Pipeline per launch (ws re-poisoned every call, so CSR is rebuilt):
//   1. init_count (self-loop = 1)          2. count edges (atomicAdd)
//   3. single-block scan -> row_start, seed self-loop into csr, init cursor
//   4. fill csr_src by dst (atomicAdd cursor)
//   5. sgemm  h1 = x @ W1            [20000,128]x[128,512]  fp32
//   6. alpha1 (per-(n,h) wave dot)   7. aggregate1 -> h2 (softmax+mean+b1+elu)
//   8. sgemm  g2 = h2 @ W2           9. alpha2     10. aggregate2 -> out
// ---------------------------------------------------------------------------

__global__ void init_count_kernel(int* __restrict__ cnt, int N) {
    int i = blockIdx.x * blockDim.x + threadIdx.x;
    if (i < N) cnt[i] = 1;  // self-loop
}

__global__ void count_kernel(const int* __restrict__ dst, int* __restrict__ cnt, int E) {
    int i = blockIdx.x * blockDim.x + threadIdx.x;
    if (i < E) atomicAdd(&cnt[dst[i]], 1);
}

// Single block, 1024 threads. Exclusive scan of cnt -> row_start[N+1].
// Also seeds the self-loop edge at the head of each segment and initializes
// the fill cursor (reusing cnt) to row_start+1.
__global__ void scan_kernel(int* __restrict__ cnt_cursor,
                            int* __restrict__ row_start,
                            int* __restrict__ csr_src, int N) {
    const int tid = threadIdx.x;
    const int IT = (N + 1023) / 1024;
    constexpr int MAX_IT = 32;
    if (IT > MAX_IT) return;  // never for N=20000

    int local[MAX_IT];
    int sum = 0;
    const int base_i = tid * IT;
    for (int k = 0; k < IT; ++k) {
        int i = base_i + k;
        int v = (i < N) ? cnt_cursor[i] : 0;
        local[k] = v;
        sum += v;
    }
    __shared__ int part[1024];
    part[tid] = sum;
    __syncthreads();
    for (int off = 1; off < 1024; off <<= 1) {
        int add = (tid >= off) ? part[tid - off] : 0;
        __syncthreads();
        part[tid] += add;
        __syncthreads();
    }
    int run = part[tid] - sum;  // exclusive prefix of this thread's range
    for (int k = 0; k < IT; ++k) {
        int i = base_i + k;
        if (i < N) {
            row_start[i] = run;
            csr_src[run] = i;          // self-loop occupies slot 0 of segment
            cnt_cursor[i] = run + 1;   // cursor for edge fill
            run += local[k];
        }
    }
    if (tid == 1023) row_start[N] = part[1023];
}

__global__ void fill_kernel(const int* __restrict__ src, const int* __restrict__ dst,
                            int* __restrict__ cursor, int* __restrict__ csr_src, int E) {
    int i = blockIdx.x * blockDim.x + threadIdx.x;
    if (i < E) {
        int pos = atomicAdd(&cursor[dst[i]], 1);
        csr_src[pos] = src[i];
    }
}

// ---------------------------------------------------------------------------
// fp32 GEMM: C[M,N] = A[M,K] @ B[K,N].  BM=128 BN=64 BK=32, 256 thr, 8x4/thr.
// ---------------------------------------------------------------------------
template <int BM, int BN, int BK, int TM, int TN>
__launch_bounds__(256)
__global__ void sgemm_kernel(const float* __restrict__ A, const float* __restrict__ B,
                             float* __restrict__ C, int M, int N, int K) {
    __shared__ float As[BK][BM + 4];  // +4 pad keeps 16B alignment, breaks bank conflicts
    __shared__ float Bs[BK][BN];

    const int tid = threadIdx.x;
    const int tn = tid % (BN / TN);  // 0..15
    const int tm = tid / (BN / TN);  // 0..15
    const int m0 = blockIdx.y * BM;
    const int n0 = blockIdx.x * BN;

    float acc[TM][TN] = {};

    for (int k0 = 0; k0 < K; k0 += BK) {
        constexpr int A_F4 = BM * BK / 4;
        for (int i = tid; i < A_F4; i += 256) {
            int r = i / (BK / 4);
            int cq = i % (BK / 4);
            int gr = m0 + r;
            if (gr >= M) gr = M - 1;  // clamp; garbage rows never stored
            float4 v = *(const float4*)&A[(size_t)gr * K + k0 + cq * 4];
            As[cq * 4 + 0][r] = v.x;
            As[cq * 4 + 1][r] = v.y;
            As[cq * 4 + 2][r] = v.z;
            As[cq * 4 + 3][r] = v.w;
        }
        constexpr int B_F4 = BK * BN / 4;
        for (int i = tid; i < B_F4; i += 256) {
            int r = i / (BN / 4);
            int cq = i % (BN / 4);
            *(float4*)&Bs[r][cq * 4] = *(const float4*)&B[(size_t)(k0 + r) * N + n0 + cq * 4];
        }
        __syncthreads();
#pragma unroll
        for (int k = 0; k < BK; ++k) {
            float a[TM], b[TN];
#pragma unroll
            for (int i = 0; i < TM; i += 4)
                *(float4*)&a[i] = *(const float4*)&As[k][tm * TM + i];
#pragma unroll
            for (int j = 0; j < TN; j += 4)
                *(float4*)&b[j] = *(const float4*)&Bs[k][tn * TN + j];
#pragma unroll
            for (int i = 0; i < TM; ++i)
#pragma unroll
                for (int j = 0; j < TN; ++j)
                    acc[i][j] = fmaf(a[i], b[j], acc[i][j]);
        }
        __syncthreads();
    }

    for (int i = 0; i < TM; ++i) {
        int gm = m0 + tm * TM + i;
        if (gm < M) {
#pragma unroll
            for (int j = 0; j < TN; j += 4) {
                float4 v = make_float4(acc[i][j], acc[i][j + 1], acc[i][j + 2], acc[i][j + 3]);
                *(float4*)&C[(size_t)gm * N + n0 + tn * TN + j] = v;
            }
        }
    }
}

// ---------------------------------------------------------------------------
// alpha_src[n,h] = <h[n,h,:], a_src[h,:]>, alpha_dst likewise. 1 wave/(n,h).
// ---------------------------------------------------------------------------
template <int H, int C>
__global__ void alpha_kernel(const float* __restrict__ h,
                             const float* __restrict__ a_src, const float* __restrict__ a_dst,
                             float* __restrict__ asrc, float* __restrict__ adst, int N) {
    int gid = blockIdx.x * blockDim.x + threadIdx.x;
    int wid = gid >> 6;
    int lane = threadIdx.x & 63;
    if (wid >= N * H) return;
    int n = wid / H, hh = wid % H;
    const float* hp = h + (size_t)n * H * C + hh * C;
    float s1 = 0.f, s2 = 0.f;
    for (int c = lane; c < C; c += 64) {
        float v = hp[c];
        s1 += v * a_src[hh * C + c];
        s2 += v * a_dst[hh * C + c];
    }
#pragma unroll
    for (int off = 32; off; off >>= 1) {
        s1 += __shfl_down(s1, off);
        s2 += __shfl_down(s2, off);
    }
    if (lane == 0) {
        asrc[wid] = s1;
        adst[wid] = s2;
    }
}

// ---------------------------------------------------------------------------
// Per-destination softmax-attention aggregate. One block per node.
//   phase A (wave 0): per-head max + exp-sum via shuffle reductions
//   phase B (all):    chunked weight precompute into LDS, then coalesced
//                     vectorized gather-accumulate of h[src] rows
//   epilogue:         head mean + bias + elu
// ---------------------------------------------------------------------------
template <int H, int C, int THREADS>
__launch_bounds__(THREADS)
__global__ void gat_aggregate_kernel(const float* __restrict__ h,     // [N, H*C]
                                     const float* __restrict__ asrc,  // [N*H]
                                     const float* __restrict__ adst,  // [N*H]
                                     const int* __restrict__ row_start,
                                     const int* __restrict__ csr_src,
                                     const float* __restrict__ bias,  // [C]
                                     float* __restrict__ out,         // [N, C]
                                     int N) {
    constexpr int SLOTS = H * C;
    constexpr int VEC = SLOTS / THREADS;  // 4 (layer1) or 2 (layer2)
    constexpr int CHUNK = 64;
    static_assert(VEC == 2 || VEC == 4, "VEC");

    const int n = blockIdx.x;
    const int tid = threadIdx.x;
    const int base = row_start[n];
    const int deg = row_start[n + 1] - base;  // >= 1 (self-loop)

    __shared__ float s_m[H], s_rden[H];
    __shared__ float s_w[CHUNK * H];
    __shared__ int s_src[CHUNK];
    __shared__ float s_acc[SLOTS];

    float adst_n[H];
#pragma unroll
    for (int i = 0; i < H; ++i) adst_n[i] = adst[(size_t)n * H + i];

    if (tid < 64) {
        float lmax[H];
#pragma unroll
        for (int i = 0; i < H; ++i) lmax[i] = -1e30f;
        for (int i = tid; i < deg; i += 64) {
            int s = csr_src[base + i];
#pragma unroll
            for (int hh = 0; hh < H; ++hh) {
                float e = asrc[(size_t)s * H + hh] + adst_n[hh];
                e = e > 0.f ? e : 0.2f * e;
                lmax[hh] = fmaxf(lmax[hh], e);
            }
        }
#pragma unroll
        for (int off = 32; off; off >>= 1)
#pragma unroll
            for (int hh = 0; hh < H; ++hh)
                lmax[hh] = fmaxf(lmax[hh], __shfl_down(lmax[hh], off));
#pragma unroll
        for (int hh = 0; hh < H; ++hh) lmax[hh] = __shfl(lmax[hh], 0);

        float lsum[H] = {};
        for (int i = tid; i < deg; i += 64) {
            int s = csr_src[base + i];
#pragma unroll
            for (int hh = 0; hh < H; ++hh) {
                float e = asrc[(size_t)s * H + hh] + adst_n[hh];
                e = e > 0.f ? e : 0.2f * e;
                lsum[hh] += __expf(e - lmax[hh]);
            }
        }
#pragma unroll
        for (int off = 32; off; off >>= 1)
#pragma unroll
            for (int hh = 0; hh < H; ++hh) lsum[hh] += __shfl_down(lsum[hh], off);
        if (tid == 0) {
#pragma unroll
            for (int hh = 0; hh < H; ++hh) {
                s_m[hh] = lmax[hh];
                s_rden[hh] = 1.0f / lsum[hh];
            }
        }
    }
    __syncthreads();

    float m_r[H], rd_r[H];
#pragma unroll
    for (int hh = 0; hh < H; ++hh) {
        m_r[hh] = s_m[hh];
        rd_r[hh] = s_rden[hh];
    }

    float acc[VEC] = {};
    const int slot0 = tid * VEC;       // contiguous VEC slots, all in one head
    const int hh_r = slot0 / C;

    auto body = [&](int j) {
        int s = s_src[j];
        float w = s_w[j * H + hh_r];
        const float* hp = &h[(size_t)s * SLOTS + slot0];
        if constexpr (VEC == 4) {
            float4 hv = *(const float4*)hp;
            acc[0] += w * hv.x;
            acc[1] += w * hv.y;
            acc[2] += w * hv.z;
            acc[3] += w * hv.w;
        } else {
            float2 hv = *(const float2*)hp;
            acc[0] += w * hv.x;
            acc[1] += w * hv.y;
        }
    };

    for (int i0 = 0; i0 < deg; i0 += CHUNK) {
        const int cnt = min(CHUNK, deg - i0);
        __syncthreads();  // protect s_w/s_src reuse
        if (tid < cnt) {
            int s = csr_src[base + i0 + tid];
            s_src[tid] = s;
#pragma unroll
            for (int hh = 0; hh < H; ++hh) {
                float e = asrc[(size_t)s * H + hh] + adst_n[hh];
                e = e > 0.f ? e : 0.2f * e;
                s_w[tid * H + hh] = __expf(e - m_r[hh]) * rd_r[hh];
            }
        }
        __syncthreads();
        if (cnt == CHUNK) {
#pragma unroll 4
            for (int j = 0; j < CHUNK; ++j) body(j);
        } else {
            for (int j = 0; j < cnt; ++j) body(j);
        }
    }

#pragma unroll
    for (int v = 0; v < VEC; ++v) s_acc[slot0 + v] = acc[v];
    __syncthreads();

    for (int c = tid; c < C; c += THREADS) {
        float t = 0.f;
#pragma unroll
        for (int hh = 0; hh < H; ++hh) t += s_acc[hh * C + c];
        t = t * (1.0f / H) + bias[c];
        t = t > 0.f ? t : (__expf(t) - 1.0f);  // elu
        out[(size_t)n * C + c] = t;
    }
}

// ---------------------------------------------------------------------------

extern "C" void kernel_launch(void* const* d_in, const int* in_sizes, int n_in,
                              void* d_out, int out_size, void* d_ws, size_t ws_size,
                              hipStream_t stream) {
    const float* x = (const float*)d_in[0];
    const float* W1 = (const float*)d_in[1];
    const float* a_src1 = (const float*)d_in[2];
    const float* a_dst1 = (const float*)d_in[3];
    const float* b1 = (const float*)d_in[4];
    const float* W2 = (const float*)d_in[5];
    const float* a_src2 = (const float*)d_in[6];
    const float* a_dst2 = (const float*)d_in[7];
    const float* b2 = (const float*)d_in[8];
    const int* edge = (const int*)d_in[9];
    float* out = (float*)d_out;

    constexpr int F = 128, H = 4;
    const int N = in_sizes[0] / F;  // 20000
    const int E = in_sizes[9] / 2;  // 640000
    const int NE = N + E;

    char* ws = (char*)d_ws;
    size_t o = 0;
    auto take = [&](size_t bytes) {
        char* p = ws + o;
        o = (o + bytes + 255) & ~(size_t)255;
        return p;
    };
    int* cnt = (int*)take((size_t)N * 4);
    int* row_start = (int*)take((size_t)(N + 1) * 4);
    int* csr_src = (int*)take((size_t)NE * 4);
    float* h1 = (float*)take((size_t)N * H * F * 4);
    float* as1 = (float*)take((size_t)N * H * 4);
    float* ad1 = (float*)take((size_t)N * H * 4);
    float* h2 = (float*)take((size_t)N * F * 4);
    float* g2 = (float*)take((size_t)N * F * 4);
    float* as2 = (float*)take((size_t)N * 4);
    float* ad2 = (float*)take((size_t)N * 4);
    (void)ws_size;

    const int* esrc = edge;
    const int* edst = edge + E;

    // ---- CSR build (by destination) ----
    hipLaunchKernelGGL(init_count_kernel, dim3((N + 255) / 256), dim3(256), 0, stream, cnt, N);
    hipLaunchKernelGGL(count_kernel, dim3((E + 255) / 256), dim3(256), 0, stream, edst, cnt, E);
    hipLaunchKernelGGL(scan_kernel, dim3(1), dim3(1024), 0, stream, cnt, row_start, csr_src, N);
    hipLaunchKernelGGL(fill_kernel, dim3((E + 255) / 256), dim3(256), 0, stream, esrc, edst, cnt,
                       csr_src, E);

    // ---- layer 1 ----
    hipLaunchKernelGGL((sgemm_kernel<128, 64, 32, 8, 4>), dim3((H * F) / 64, (N + 127) / 128),
                       dim3(256), 0, stream, x, W1, h1, N, H * F, F);
    hipLaunchKernelGGL((alpha_kernel<H, F>), dim3((N * H * 64 + 255) / 256), dim3(256), 0, stream,
                       h1, a_src1, a_dst1, as1, ad1, N);
    hipLaunchKernelGGL((gat_aggregate_kernel<H, F, 128>), dim3(N), dim3(128), 0, stream, h1, as1,
                       ad1, row_start, csr_src, b1, h2, N);

    // ---- layer 2 ----
    hipLaunchKernelGGL((sgemm_kernel<128, 64, 32, 8, 4>), dim3(F / 64, (N + 127) / 128), dim3(256),
                       0, stream, h2, W2, g2, N, F, F);
    hipLaunchKernelGGL((alpha_kernel<1, F>), dim3((N * 64 + 255) / 256), dim3(256), 0, stream, g2,
                       a_src2, a_dst2, as2, ad2, N);
    hipLaunchKernelGGL((gat_aggregate_kernel<1, F, 64>), dim3(N), dim3(64), 0, stream, g2, as2,
                       ad2, row_start, csr_src, b2, out, N);
}

// Round 2
// 370.370 us; speedup vs baseline: 1.2905x; 1.2905x over previous
//
#include <hip/hip_runtime.h>
#include <hip/hip_bf16.h>

// ---------------------------------------------------------------------------
// 2-layer GAT (PyG GATConv semantics, concat=False -> head mean, self-loops)
// Round 2: all node-feature tensors consumed by the edge-gather (h1, g2) are
// stored ONLY in bf16 (fp32 accumulation everywhere). This halves the
// L2-miss/LLC gather traffic that round-1 profiling showed to be the
// bottleneck (aggregate1: 174 us, FETCH_SIZE 615 MB, VALUBusy 14.7%).
// ---------------------------------------------------------------------------

__device__ __forceinline__ float bf2f(unsigned short u) {
    union { unsigned int i; float f; } v;
    v.i = (unsigned int)u << 16;
    return v.f;
}
__device__ __forceinline__ unsigned short f2bf(float f) {
    union { float f; unsigned int i; } v;
    v.f = f;
    unsigned int lsb = (v.i >> 16) & 1u;
    v.i += 0x7fffu + lsb;  // round-to-nearest-even (finite values only)
    return (unsigned short)(v.i >> 16);
}

__global__ void init_count_kernel(int* __restrict__ cnt, int N) {
    int i = blockIdx.x * blockDim.x + threadIdx.x;
    if (i < N) cnt[i] = 1;  // self-loop
}

__global__ void count_kernel(const int* __restrict__ dst, int* __restrict__ cnt, int E) {
    int i = blockIdx.x * blockDim.x + threadIdx.x;
    if (i < E) atomicAdd(&cnt[dst[i]], 1);
}

// Single block, 1024 threads. Exclusive scan of cnt -> row_start[N+1].
// Seeds the self-loop at the head of each segment; cursor = row_start+1.
__global__ void scan_kernel(int* __restrict__ cnt_cursor,
                            int* __restrict__ row_start,
                            int* __restrict__ csr_src, int N) {
    const int tid = threadIdx.x;
    const int IT = (N + 1023) / 1024;
    constexpr int MAX_IT = 32;
    if (IT > MAX_IT) return;

    int local[MAX_IT];
    int sum = 0;
    const int base_i = tid * IT;
    for (int k = 0; k < IT; ++k) {
        int i = base_i + k;
        int v = (i < N) ? cnt_cursor[i] : 0;
        local[k] = v;
        sum += v;
    }
    __shared__ int part[1024];
    part[tid] = sum;
    __syncthreads();
    for (int off = 1; off < 1024; off <<= 1) {
        int add = (tid >= off) ? part[tid - off] : 0;
        __syncthreads();
        part[tid] += add;
        __syncthreads();
    }
    int run = part[tid] - sum;
    for (int k = 0; k < IT; ++k) {
        int i = base_i + k;
        if (i < N) {
            row_start[i] = run;
            csr_src[run] = i;
            cnt_cursor[i] = run + 1;
            run += local[k];
        }
    }
    if (tid == 1023) row_start[N] = part[1023];
}

__global__ void fill_kernel(const int* __restrict__ src, const int* __restrict__ dst,
                            int* __restrict__ cursor, int* __restrict__ csr_src, int E) {
    int i = blockIdx.x * blockDim.x + threadIdx.x;
    if (i < E) {
        int pos = atomicAdd(&cursor[dst[i]], 1);
        csr_src[pos] = src[i];
    }
}

// ---------------------------------------------------------------------------
// fp32 GEMM, bf16 output: C[M,N] = bf16(A[M,K] @ B[K,N]).
// BM=128 BN=64 BK=32, 256 thr, 8x4 per thread.
// ---------------------------------------------------------------------------
template <int BM, int BN, int BK, int TM, int TN>
__launch_bounds__(256)
__global__ void sgemm_bf16_kernel(const float* __restrict__ A, const float* __restrict__ B,
                                  unsigned short* __restrict__ C, int M, int N, int K) {
    __shared__ float As[BK][BM + 4];
    __shared__ float Bs[BK][BN];

    const int tid = threadIdx.x;
    const int tn = tid % (BN / TN);
    const int tm = tid / (BN / TN);
    const int m0 = blockIdx.y * BM;
    const int n0 = blockIdx.x * BN;

    float acc[TM][TN] = {};

    for (int k0 = 0; k0 < K; k0 += BK) {
        constexpr int A_F4 = BM * BK / 4;
        for (int i = tid; i < A_F4; i += 256) {
            int r = i / (BK / 4);
            int cq = i % (BK / 4);
            int gr = m0 + r;
            if (gr >= M) gr = M - 1;  // clamp; garbage rows never stored
            float4 v = *(const float4*)&A[(size_t)gr * K + k0 + cq * 4];
            As[cq * 4 + 0][r] = v.x;
            As[cq * 4 + 1][r] = v.y;
            As[cq * 4 + 2][r] = v.z;
            As[cq * 4 + 3][r] = v.w;
        }
        constexpr int B_F4 = BK * BN / 4;
        for (int i = tid; i < B_F4; i += 256) {
            int r = i / (BN / 4);
            int cq = i % (BN / 4);
            *(float4*)&Bs[r][cq * 4] = *(const float4*)&B[(size_t)(k0 + r) * N + n0 + cq * 4];
        }
        __syncthreads();
#pragma unroll
        for (int k = 0; k < BK; ++k) {
            float a[TM], b[TN];
#pragma unroll
            for (int i = 0; i < TM; i += 4)
                *(float4*)&a[i] = *(const float4*)&As[k][tm * TM + i];
#pragma unroll
            for (int j = 0; j < TN; j += 4)
                *(float4*)&b[j] = *(const float4*)&Bs[k][tn * TN + j];
#pragma unroll
            for (int i = 0; i < TM; ++i)
#pragma unroll
                for (int j = 0; j < TN; ++j)
                    acc[i][j] = fmaf(a[i], b[j], acc[i][j]);
        }
        __syncthreads();
    }

    for (int i = 0; i < TM; ++i) {
        int gm = m0 + tm * TM + i;
        if (gm < M) {
#pragma unroll
            for (int j = 0; j < TN; j += 4) {
                ushort4 v;
                v.x = f2bf(acc[i][j + 0]);
                v.y = f2bf(acc[i][j + 1]);
                v.z = f2bf(acc[i][j + 2]);
                v.w = f2bf(acc[i][j + 3]);
                *(ushort4*)&C[(size_t)gm * N + n0 + tn * TN + j] = v;
            }
        }
    }
}

// ---------------------------------------------------------------------------
// alpha_src[n,h] = <h[n,h,:], a_src[h,:]> (h in bf16, accum fp32). 1 wave/(n,h).
// ---------------------------------------------------------------------------
template <int H, int C>
__global__ void alpha_kernel(const unsigned short* __restrict__ h,
                             const float* __restrict__ a_src, const float* __restrict__ a_dst,
                             float* __restrict__ asrc, float* __restrict__ adst, int N) {
    int gid = blockIdx.x * blockDim.x + threadIdx.x;
    int wid = gid >> 6;
    int lane = threadIdx.x & 63;
    if (wid >= N * H) return;
    int n = wid / H, hh = wid % H;
    const unsigned short* hp = h + (size_t)n * H * C + hh * C;
    float s1 = 0.f, s2 = 0.f;
    for (int c = lane; c < C; c += 64) {
        float v = bf2f(hp[c]);
        s1 += v * a_src[hh * C + c];
        s2 += v * a_dst[hh * C + c];
    }
#pragma unroll
    for (int off = 32; off; off >>= 1) {
        s1 += __shfl_down(s1, off);
        s2 += __shfl_down(s2, off);
    }
    if (lane == 0) {
        asrc[wid] = s1;
        adst[wid] = s2;
    }
}

// ---------------------------------------------------------------------------
// Per-destination softmax-attention aggregate, bf16 gather, fp32 accumulate.
// One block per node.
// ---------------------------------------------------------------------------
template <int H, int C, int THREADS>
__launch_bounds__(THREADS)
__global__ void gat_aggregate_kernel(const unsigned short* __restrict__ h,  // [N, H*C] bf16
                                     const float* __restrict__ asrc,        // [N*H]
                                     const float* __restrict__ adst,        // [N*H]
                                     const int* __restrict__ row_start,
                                     const int* __restrict__ csr_src,
                                     const float* __restrict__ bias,  // [C]
                                     float* __restrict__ out,         // [N, C] fp32
                                     int N) {
    constexpr int SLOTS = H * C;
    constexpr int VEC = SLOTS / THREADS;  // 4 (layer1) or 2 (layer2)
    constexpr int CHUNK = 64;
    static_assert(VEC == 2 || VEC == 4, "VEC");

    const int n = blockIdx.x;
    const int tid = threadIdx.x;
    const int base = row_start[n];
    const int deg = row_start[n + 1] - base;  // >= 1 (self-loop)

    __shared__ float s_m[H], s_rden[H];
    __shared__ float s_w[CHUNK * H];
    __shared__ int s_src[CHUNK];
    __shared__ float s_acc[SLOTS];

    float adst_n[H];
#pragma unroll
    for (int i = 0; i < H; ++i) adst_n[i] = adst[(size_t)n * H + i];

    if (tid < 64) {
        float lmax[H];
#pragma unroll
        for (int i = 0; i < H; ++i) lmax[i] = -1e30f;
        for (int i = tid; i < deg; i += 64) {
            int s = csr_src[base + i];
#pragma unroll
            for (int hh = 0; hh < H; ++hh) {
                float e = asrc[(size_t)s * H + hh] + adst_n[hh];
                e = e > 0.f ? e : 0.2f * e;
                lmax[hh] = fmaxf(lmax[hh], e);
            }
        }
#pragma unroll
        for (int off = 32; off; off >>= 1)
#pragma unroll
            for (int hh = 0; hh < H; ++hh)
                lmax[hh] = fmaxf(lmax[hh], __shfl_down(lmax[hh], off));
#pragma unroll
        for (int hh = 0; hh < H; ++hh) lmax[hh] = __shfl(lmax[hh], 0);

        float lsum[H] = {};
        for (int i = tid; i < deg; i += 64) {
            int s = csr_src[base + i];
#pragma unroll
            for (int hh = 0; hh < H; ++hh) {
                float e = asrc[(size_t)s * H + hh] + adst_n[hh];
                e = e > 0.f ? e : 0.2f * e;
                lsum[hh] += __expf(e - lmax[hh]);
            }
        }
#pragma unroll
        for (int off = 32; off; off >>= 1)
#pragma unroll
            for (int hh = 0; hh < H; ++hh) lsum[hh] += __shfl_down(lsum[hh], off);
        if (tid == 0) {
#pragma unroll
            for (int hh = 0; hh < H; ++hh) {
                s_m[hh] = lmax[hh];
                s_rden[hh] = 1.0f / lsum[hh];
            }
        }
    }
    __syncthreads();

    float m_r[H], rd_r[H];
#pragma unroll
    for (int hh = 0; hh < H; ++hh) {
        m_r[hh] = s_m[hh];
        rd_r[hh] = s_rden[hh];
    }

    float acc[VEC] = {};
    const int slot0 = tid * VEC;  // contiguous VEC slots, all in one head
    const int hh_r = slot0 / C;

    auto body = [&](int j) {
        int s = s_src[j];
        float w = s_w[j * H + hh_r];
        const unsigned short* hp = &h[(size_t)s * SLOTS + slot0];
        if constexpr (VEC == 4) {
            ushort4 hv = *(const ushort4*)hp;
            acc[0] += w * bf2f(hv.x);
            acc[1] += w * bf2f(hv.y);
            acc[2] += w * bf2f(hv.z);
            acc[3] += w * bf2f(hv.w);
        } else {
            ushort2 hv = *(const ushort2*)hp;
            acc[0] += w * bf2f(hv.x);
            acc[1] += w * bf2f(hv.y);
        }
    };

    for (int i0 = 0; i0 < deg; i0 += CHUNK) {
        const int cnt = min(CHUNK, deg - i0);
        __syncthreads();  // protect s_w/s_src reuse
        if (tid < cnt) {
            int s = csr_src[base + i0 + tid];
            s_src[tid] = s;
#pragma unroll
            for (int hh = 0; hh < H; ++hh) {
                float e = asrc[(size_t)s * H + hh] + adst_n[hh];
                e = e > 0.f ? e : 0.2f * e;
                s_w[tid * H + hh] = __expf(e - m_r[hh]) * rd_r[hh];
            }
        }
        __syncthreads();
        if (cnt == CHUNK) {
#pragma unroll 4
            for (int j = 0; j < CHUNK; ++j) body(j);
        } else {
            for (int j = 0; j < cnt; ++j) body(j);
        }
    }

#pragma unroll
    for (int v = 0; v < VEC; ++v) s_acc[slot0 + v] = acc[v];
    __syncthreads();

    for (int c = tid; c < C; c += THREADS) {
        float t = 0.f;
#pragma unroll
        for (int hh = 0; hh < H; ++hh) t += s_acc[hh * C + c];
        t = t * (1.0f / H) + bias[c];
        t = t > 0.f ? t : (__expf(t) - 1.0f);  // elu
        out[(size_t)n * C + c] = t;
    }
}

// ---------------------------------------------------------------------------

extern "C" void kernel_launch(void* const* d_in, const int* in_sizes, int n_in,
                              void* d_out, int out_size, void* d_ws, size_t ws_size,
                              hipStream_t stream) {
    const float* x = (const float*)d_in[0];
    const float* W1 = (const float*)d_in[1];
    const float* a_src1 = (const float*)d_in[2];
    const float* a_dst1 = (const float*)d_in[3];
    const float* b1 = (const float*)d_in[4];
    const float* W2 = (const float*)d_in[5];
    const float* a_src2 = (const float*)d_in[6];
    const float* a_dst2 = (const float*)d_in[7];
    const float* b2 = (const float*)d_in[8];
    const int* edge = (const int*)d_in[9];
    float* out = (float*)d_out;

    constexpr int F = 128, H = 4;
    const int N = in_sizes[0] / F;  // 20000
    const int E = in_sizes[9] / 2;  // 640000
    const int NE = N + E;

    char* ws = (char*)d_ws;
    size_t o = 0;
    auto take = [&](size_t bytes) {
        char* p = ws + o;
        o = (o + bytes + 255) & ~(size_t)255;
        return p;
    };
    int* cnt = (int*)take((size_t)N * 4);
    int* row_start = (int*)take((size_t)(N + 1) * 4);
    int* csr_src = (int*)take((size_t)NE * 4);
    unsigned short* h1b = (unsigned short*)take((size_t)N * H * F * 2);  // bf16
    float* as1 = (float*)take((size_t)N * H * 4);
    float* ad1 = (float*)take((size_t)N * H * 4);
    float* h2 = (float*)take((size_t)N * F * 4);                          // fp32 (GEMM2 input)
    unsigned short* g2b = (unsigned short*)take((size_t)N * F * 2);       // bf16
    float* as2 = (float*)take((size_t)N * 4);
    float* ad2 = (float*)take((size_t)N * 4);
    (void)ws_size;

    const int* esrc = edge;
    const int* edst = edge + E;

    // ---- CSR build (by destination) ----
    hipLaunchKernelGGL(init_count_kernel, dim3((N + 255) / 256), dim3(256), 0, stream, cnt, N);
    hipLaunchKernelGGL(count_kernel, dim3((E + 255) / 256), dim3(256), 0, stream, edst, cnt, E);
    hipLaunchKernelGGL(scan_kernel, dim3(1), dim3(1024), 0, stream, cnt, row_start, csr_src, N);
    hipLaunchKernelGGL(fill_kernel, dim3((E + 255) / 256), dim3(256), 0, stream, esrc, edst, cnt,
                       csr_src, E);

    // ---- layer 1 ----
    hipLaunchKernelGGL((sgemm_bf16_kernel<128, 64, 32, 8, 4>), dim3((H * F) / 64, (N + 127) / 128),
                       dim3(256), 0, stream, x, W1, h1b, N, H * F, F);
    hipLaunchKernelGGL((alpha_kernel<H, F>), dim3((N * H * 64 + 255) / 256), dim3(256), 0, stream,
                       h1b, a_src1, a_dst1, as1, ad1, N);
    hipLaunchKernelGGL((gat_aggregate_kernel<H, F, 128>), dim3(N), dim3(128), 0, stream, h1b, as1,
                       ad1, row_start, csr_src, b1, h2, N);

    // ---- layer 2 ----
    hipLaunchKernelGGL((sgemm_bf16_kernel<128, 64, 32, 8, 4>), dim3(F / 64, (N + 127) / 128),
                       dim3(256), 0, stream, h2, W2, g2b, N, F, F);
    hipLaunchKernelGGL((alpha_kernel<1, F>), dim3((N * 64 + 255) / 256), dim3(256), 0, stream, g2b,
                       a_src2, a_dst2, as2, ad2, N);
    hipLaunchKernelGGL((gat_aggregate_kernel<1, F, 64>), dim3(N), dim3(64), 0, stream, g2b, as2,
                       ad2, row_start, csr_src, b2, out, N);
}

// Round 3
// 339.033 us; speedup vs baseline: 1.4098x; 1.0924x over previous
//
#include <hip/hip_runtime.h>
#include <hip/hip_bf16.h>

// ---------------------------------------------------------------------------
// 2-layer GAT (PyG GATConv, concat=False -> head mean, self-loops).
// Round 3:
//  - GEMMs moved to bf16 MFMA (v_mfma_f32_16x16x32_bf16, fp32 accum); x and
//    W1/W2 cast (W pre-transposed to [N][K]) in tiny prep kernels. The whole
//    inter-layer feature path (h1, h2, g2) is bf16 now.
//  - Layer-1 aggregate: 64 thr / VEC=8 -> one wave reads a full 1KB row with
//    a single global_load_dwordx4 per edge; unroll 8 for MLP.
// ---------------------------------------------------------------------------

typedef short v8s __attribute__((ext_vector_type(8)));
typedef float v4f __attribute__((ext_vector_type(4)));

__device__ __forceinline__ float bf2f(unsigned short u) {
    union { unsigned int i; float f; } v;
    v.i = (unsigned int)u << 16;
    return v.f;
}
__device__ __forceinline__ void bf2x(unsigned int u, float& lo, float& hi) {
    union { unsigned int i; float f; } a, b;
    a.i = u << 16;
    b.i = u & 0xffff0000u;
    lo = a.f;
    hi = b.f;
}
__device__ __forceinline__ unsigned short f2bf(float f) {
    union { float f; unsigned int i; } v;
    v.f = f;
    unsigned int lsb = (v.i >> 16) & 1u;
    v.i += 0x7fffu + lsb;  // RNE (finite values only)
    return (unsigned short)(v.i >> 16);
}

// ---------------------------- CSR build ------------------------------------

__global__ void init_count_kernel(int* __restrict__ cnt, int N) {
    int i = blockIdx.x * blockDim.x + threadIdx.x;
    if (i < N) cnt[i] = 1;  // self-loop
}

__global__ void count_kernel(const int* __restrict__ dst, int* __restrict__ cnt, int E) {
    int i = blockIdx.x * blockDim.x + threadIdx.x;
    if (i < E) atomicAdd(&cnt[dst[i]], 1);
}

// Single block, 1024 threads. Exclusive scan -> row_start[N+1]; seeds the
// self-loop at segment head; cursor (reusing cnt) = row_start+1.
__global__ void scan_kernel(int* __restrict__ cnt_cursor,
                            int* __restrict__ row_start,
                            int* __restrict__ csr_src, int N) {
    const int tid = threadIdx.x;
    const int IT = (N + 1023) / 1024;
    constexpr int MAX_IT = 32;
    if (IT > MAX_IT) return;

    int local[MAX_IT];
    int sum = 0;
    const int base_i = tid * IT;
    for (int k = 0; k < IT; ++k) {
        int i = base_i + k;
        int v = (i < N) ? cnt_cursor[i] : 0;
        local[k] = v;
        sum += v;
    }
    __shared__ int part[1024];
    part[tid] = sum;
    __syncthreads();
    for (int off = 1; off < 1024; off <<= 1) {
        int add = (tid >= off) ? part[tid - off] : 0;
        __syncthreads();
        part[tid] += add;
        __syncthreads();
    }
    int run = part[tid] - sum;
    for (int k = 0; k < IT; ++k) {
        int i = base_i + k;
        if (i < N) {
            row_start[i] = run;
            csr_src[run] = i;
            cnt_cursor[i] = run + 1;
            run += local[k];
        }
    }
    if (tid == 1023) row_start[N] = part[1023];
}

__global__ void fill_kernel(const int* __restrict__ src, const int* __restrict__ dst,
                            int* __restrict__ cursor, int* __restrict__ csr_src, int E) {
    int i = blockIdx.x * blockDim.x + threadIdx.x;
    if (i < E) {
        int pos = atomicAdd(&cursor[dst[i]], 1);
        csr_src[pos] = src[i];
    }
}

// ---------------------------- casts ----------------------------------------

__global__ void cast_f32_bf16_kernel(const float* __restrict__ in,
                                     unsigned short* __restrict__ out, int n) {
    int i = (blockIdx.x * blockDim.x + threadIdx.x) * 4;
    if (i + 3 < n) {
        float4 v = *(const float4*)&in[i];
        ushort4 o;
        o.x = f2bf(v.x);
        o.y = f2bf(v.y);
        o.z = f2bf(v.z);
        o.w = f2bf(v.w);
        *(ushort4*)&out[i] = o;
    } else {
        for (; i < n; ++i) out[i] = f2bf(in[i]);
    }
}

// W[K][N] fp32 -> Wt[N][K] bf16
__global__ void cast_transpose_kernel(const float* __restrict__ W,
                                      unsigned short* __restrict__ Wt, int K, int N) {
    int i = blockIdx.x * blockDim.x + threadIdx.x;
    if (i < K * N) {
        int k = i / N, n = i % N;
        Wt[(size_t)n * K + k] = f2bf(W[i]);
    }
}

// ---------------------------- MFMA GEMM ------------------------------------
// C[M][N] = A[M][K=128] @ Bt[N][K=128]^T, all bf16 storage, fp32 accum.
// Block: 256 thr (4 waves) -> 64x64 C tile. Wave w: rows [w*16, w*16+16).
// A/B fragments per cdna4 16x16x32 layout: A[m=lane&15][k=(lane>>4)*8+j],
// B[k=(lane>>4)*8+j][n=lane&15]; D: col=lane&15, row=(lane>>4)*4+reg.
__launch_bounds__(256)
__global__ void gemm_bf16_mfma_kernel(const unsigned short* __restrict__ A,
                                      const unsigned short* __restrict__ Bt,
                                      unsigned short* __restrict__ C, int M, int N) {
    constexpr int K = 128;
    constexpr int BK = 32;
    __shared__ unsigned short As[64][40];  // pad 32->40 (80B row = 20 banks)
    __shared__ unsigned short Bs[64][40];

    const int tid = threadIdx.x;
    const int w = tid >> 6;
    const int lane = tid & 63;
    const int m16 = lane & 15;
    const int kg = lane >> 4;
    const int m0 = blockIdx.y * 64;
    const int n0 = blockIdx.x * 64;

    v4f acc[4];
#pragma unroll
    for (int i = 0; i < 4; ++i) acc[i] = (v4f){0.f, 0.f, 0.f, 0.f};

    const int srow = tid >> 2;  // 0..63
    const int sseg = tid & 3;   // 0..3 (8 bf16 = 16B each)
    const int arow_g = min(m0 + srow, M - 1);  // clamp; tail rows never stored
    const unsigned short* Ap = &A[(size_t)arow_g * K + sseg * 8];
    const unsigned short* Bp = &Bt[(size_t)(n0 + srow) * K + sseg * 8];

    for (int k0 = 0; k0 < K; k0 += BK) {
        uint4 av = *(const uint4*)(Ap + k0);
        uint4 bv = *(const uint4*)(Bp + k0);
        __syncthreads();
        *(uint4*)&As[srow][sseg * 8] = av;
        *(uint4*)&Bs[srow][sseg * 8] = bv;
        __syncthreads();
        v8s a = *(const v8s*)&As[w * 16 + m16][kg * 8];
#pragma unroll
        for (int i = 0; i < 4; ++i) {
            v8s b = *(const v8s*)&Bs[i * 16 + m16][kg * 8];
            acc[i] = __builtin_amdgcn_mfma_f32_16x16x32_bf16(a, b, acc[i], 0, 0, 0);
        }
    }

#pragma unroll
    for (int i = 0; i < 4; ++i)
#pragma unroll
        for (int r = 0; r < 4; ++r) {
            int row = m0 + w * 16 + kg * 4 + r;
            if (row < M) C[(size_t)row * N + n0 + i * 16 + m16] = f2bf(acc[i][r]);
        }
}

// ---------------------------- alpha ----------------------------------------
// alpha_src[n,h] = <h[n,h,:], a_src[h,:]> (h bf16, accum fp32). 1 wave/(n,h).
template <int H, int C>
__global__ void alpha_kernel(const unsigned short* __restrict__ h,
                             const float* __restrict__ a_src, const float* __restrict__ a_dst,
                             float* __restrict__ asrc, float* __restrict__ adst, int N) {
    int gid = blockIdx.x * blockDim.x + threadIdx.x;
    int wid = gid >> 6;
    int lane = threadIdx.x & 63;
    if (wid >= N * H) return;
    int n = wid / H, hh = wid % H;
    const unsigned short* hp = h + (size_t)n * H * C + hh * C;
    float s1 = 0.f, s2 = 0.f;
    for (int c = lane; c < C; c += 64) {
        float v = bf2f(hp[c]);
        s1 += v * a_src[hh * C + c];
        s2 += v * a_dst[hh * C + c];
    }
#pragma unroll
    for (int off = 32; off; off >>= 1) {
        s1 += __shfl_down(s1, off);
        s2 += __shfl_down(s2, off);
    }
    if (lane == 0) {
        asrc[wid] = s1;
        adst[wid] = s2;
    }
}

// ---------------------------- aggregate ------------------------------------
__device__ __forceinline__ void store_out(float* p, float v) { *p = v; }
__device__ __forceinline__ void store_out(unsigned short* p, float v) { *p = f2bf(v); }

// Per-destination softmax-attention aggregate; bf16 gather, fp32 accumulate.
// One block per node. VEC=8 -> one dwordx4 per lane covers a full 1KB row.
template <int H, int C, int THREADS, typename OT>
__launch_bounds__(THREADS)
__global__ void gat_aggregate_kernel(const unsigned short* __restrict__ h,  // [N, H*C] bf16
                                     const float* __restrict__ asrc,        // [N*H]
                                     const float* __restrict__ adst,        // [N*H]
                                     const int* __restrict__ row_start,
                                     const int* __restrict__ csr_src,
                                     const float* __restrict__ bias,  // [C]
                                     OT* __restrict__ out,            // [N, C]
                                     int N) {
    constexpr int SLOTS = H * C;
    constexpr int VEC = SLOTS / THREADS;  // 8 (layer1) or 2 (layer2)
    constexpr int CHUNK = 64;
    static_assert(VEC == 2 || VEC == 4 || VEC == 8, "VEC");

    const int n = blockIdx.x;
    const int tid = threadIdx.x;
    const int base = row_start[n];
    const int deg = row_start[n + 1] - base;  // >= 1 (self-loop)

    __shared__ float s_m[H], s_rden[H];
    __shared__ float s_w[CHUNK * H];
    __shared__ int s_src[CHUNK];
    __shared__ float s_acc[SLOTS];

    float adst_n[H];
#pragma unroll
    for (int i = 0; i < H; ++i) adst_n[i] = adst[(size_t)n * H + i];

    if (tid < 64) {
        float lmax[H];
#pragma unroll
        for (int i = 0; i < H; ++i) lmax[i] = -1e30f;
        for (int i = tid; i < deg; i += 64) {
            int s = csr_src[base + i];
#pragma unroll
            for (int hh = 0; hh < H; ++hh) {
                float e = asrc[(size_t)s * H + hh] + adst_n[hh];
                e = e > 0.f ? e : 0.2f * e;
                lmax[hh] = fmaxf(lmax[hh], e);
            }
        }
#pragma unroll
        for (int off = 32; off; off >>= 1)
#pragma unroll
            for (int hh = 0; hh < H; ++hh)
                lmax[hh] = fmaxf(lmax[hh], __shfl_down(lmax[hh], off));
#pragma unroll
        for (int hh = 0; hh < H; ++hh) lmax[hh] = __shfl(lmax[hh], 0);

        float lsum[H] = {};
        for (int i = tid; i < deg; i += 64) {
            int s = csr_src[base + i];
#pragma unroll
            for (int hh = 0; hh < H; ++hh) {
                float e = asrc[(size_t)s * H + hh] + adst_n[hh];
                e = e > 0.f ? e : 0.2f * e;
                lsum[hh] += __expf(e - lmax[hh]);
            }
        }
#pragma unroll
        for (int off = 32; off; off >>= 1)
#pragma unroll
            for (int hh = 0; hh < H; ++hh) lsum[hh] += __shfl_down(lsum[hh], off);
        if (tid == 0) {
#pragma unroll
            for (int hh = 0; hh < H; ++hh) {
                s_m[hh] = lmax[hh];
                s_rden[hh] = 1.0f / lsum[hh];
            }
        }
    }
    __syncthreads();

    float m_r[H], rd_r[H];
#pragma unroll
    for (int hh = 0; hh < H; ++hh) {
        m_r[hh] = s_m[hh];
        rd_r[hh] = s_rden[hh];
    }

    float acc[VEC] = {};
    const int slot0 = tid * VEC;  // contiguous VEC slots, all in one head
    const int hh_r = slot0 / C;

    auto body = [&](int j) {
        int s = s_src[j];
        float wgt = s_w[j * H + hh_r];
        const unsigned short* hp = &h[(size_t)s * SLOTS + slot0];
        if constexpr (VEC == 8) {
            uint4 hv = *(const uint4*)hp;
            float f0, f1;
            bf2x(hv.x, f0, f1);
            acc[0] += wgt * f0;
            acc[1] += wgt * f1;
            bf2x(hv.y, f0, f1);
            acc[2] += wgt * f0;
            acc[3] += wgt * f1;
            bf2x(hv.z, f0, f1);
            acc[4] += wgt * f0;
            acc[5] += wgt * f1;
            bf2x(hv.w, f0, f1);
            acc[6] += wgt * f0;
            acc[7] += wgt * f1;
        } else if constexpr (VEC == 4) {
            ushort4 hv = *(const ushort4*)hp;
            acc[0] += wgt * bf2f(hv.x);
            acc[1] += wgt * bf2f(hv.y);
            acc[2] += wgt * bf2f(hv.z);
            acc[3] += wgt * bf2f(hv.w);
        } else {
            ushort2 hv = *(const ushort2*)hp;
            acc[0] += wgt * bf2f(hv.x);
            acc[1] += wgt * bf2f(hv.y);
        }
    };

    for (int i0 = 0; i0 < deg; i0 += CHUNK) {
        const int cnt = min(CHUNK, deg - i0);
        __syncthreads();  // protect s_w/s_src reuse
        if (tid < cnt) {
            int s = csr_src[base + i0 + tid];
            s_src[tid] = s;
#pragma unroll
            for (int hh = 0; hh < H; ++hh) {
                float e = asrc[(size_t)s * H + hh] + adst_n[hh];
                e = e > 0.f ? e : 0.2f * e;
                s_w[tid * H + hh] = __expf(e - m_r[hh]) * rd_r[hh];
            }
        }
        __syncthreads();
        if (cnt == CHUNK) {
#pragma unroll 8
            for (int j = 0; j < CHUNK; ++j) body(j);
        } else {
            for (int j = 0; j < cnt; ++j) body(j);
        }
    }

#pragma unroll
    for (int v = 0; v < VEC; ++v) s_acc[slot0 + v] = acc[v];
    __syncthreads();

    for (int c = tid; c < C; c += THREADS) {
        float t = 0.f;
#pragma unroll
        for (int hh = 0; hh < H; ++hh) t += s_acc[hh * C + c];
        t = t * (1.0f / H) + bias[c];
        t = t > 0.f ? t : (__expf(t) - 1.0f);  // elu
        store_out(&out[(size_t)n * C + c], t);
    }
}

// ---------------------------------------------------------------------------

extern "C" void kernel_launch(void* const* d_in, const int* in_sizes, int n_in,
                              void* d_out, int out_size, void* d_ws, size_t ws_size,
                              hipStream_t stream) {
    const float* x = (const float*)d_in[0];
    const float* W1 = (const float*)d_in[1];
    const float* a_src1 = (const float*)d_in[2];
    const float* a_dst1 = (const float*)d_in[3];
    const float* b1 = (const float*)d_in[4];
    const float* W2 = (const float*)d_in[5];
    const float* a_src2 = (const float*)d_in[6];
    const float* a_dst2 = (const float*)d_in[7];
    const float* b2 = (const float*)d_in[8];
    const int* edge = (const int*)d_in[9];
    float* out = (float*)d_out;

    constexpr int F = 128, H = 4;
    const int N = in_sizes[0] / F;  // 20000
    const int E = in_sizes[9] / 2;  // 640000
    const int NE = N + E;

    char* ws = (char*)d_ws;
    size_t o = 0;
    auto take = [&](size_t bytes) {
        char* p = ws + o;
        o = (o + bytes + 255) & ~(size_t)255;
        return p;
    };
    int* cnt = (int*)take((size_t)N * 4);
    int* row_start = (int*)take((size_t)(N + 1) * 4);
    int* csr_src = (int*)take((size_t)NE * 4);
    unsigned short* xb = (unsigned short*)take((size_t)N * F * 2);        // bf16 x
    unsigned short* W1t = (unsigned short*)take((size_t)F * H * F * 2);   // [512][128] bf16
    unsigned short* W2t = (unsigned short*)take((size_t)F * F * 2);       // [128][128] bf16
    unsigned short* h1b = (unsigned short*)take((size_t)N * H * F * 2);   // bf16
    float* as1 = (float*)take((size_t)N * H * 4);
    float* ad1 = (float*)take((size_t)N * H * 4);
    unsigned short* h2b = (unsigned short*)take((size_t)N * F * 2);       // bf16
    unsigned short* g2b = (unsigned short*)take((size_t)N * F * 2);       // bf16
    float* as2 = (float*)take((size_t)N * 4);
    float* ad2 = (float*)take((size_t)N * 4);
    (void)ws_size;

    const int* esrc = edge;
    const int* edst = edge + E;

    // ---- CSR build (by destination) ----
    hipLaunchKernelGGL(init_count_kernel, dim3((N + 255) / 256), dim3(256), 0, stream, cnt, N);
    hipLaunchKernelGGL(count_kernel, dim3((E + 255) / 256), dim3(256), 0, stream, edst, cnt, E);
    hipLaunchKernelGGL(scan_kernel, dim3(1), dim3(1024), 0, stream, cnt, row_start, csr_src, N);
    hipLaunchKernelGGL(fill_kernel, dim3((E + 255) / 256), dim3(256), 0, stream, esrc, edst, cnt,
                       csr_src, E);

    // ---- casts ----
    hipLaunchKernelGGL(cast_f32_bf16_kernel, dim3((N * F / 4 + 255) / 256), dim3(256), 0, stream,
                       x, xb, N * F);
    hipLaunchKernelGGL(cast_transpose_kernel, dim3((F * H * F + 255) / 256), dim3(256), 0, stream,
                       W1, W1t, F, H * F);
    hipLaunchKernelGGL(cast_transpose_kernel, dim3((F * F + 255) / 256), dim3(256), 0, stream,
                       W2, W2t, F, F);

    // ---- layer 1 ----
    hipLaunchKernelGGL(gemm_bf16_mfma_kernel, dim3((H * F) / 64, (N + 63) / 64), dim3(256), 0,
                       stream, xb, W1t, h1b, N, H * F);
    hipLaunchKernelGGL((alpha_kernel<H, F>), dim3((N * H * 64 + 255) / 256), dim3(256), 0, stream,
                       h1b, a_src1, a_dst1, as1, ad1, N);
    hipLaunchKernelGGL((gat_aggregate_kernel<H, F, 64, unsigned short>), dim3(N), dim3(64), 0,
                       stream, h1b, as1, ad1, row_start, csr_src, b1, h2b, N);

    // ---- layer 2 ----
    hipLaunchKernelGGL(gemm_bf16_mfma_kernel, dim3(F / 64, (N + 63) / 64), dim3(256), 0, stream,
                       h2b, W2t, g2b, N, F);
    hipLaunchKernelGGL((alpha_kernel<1, F>), dim3((N * 64 + 255) / 256), dim3(256), 0, stream, g2b,
                       a_src2, a_dst2, as2, ad2, N);
    hipLaunchKernelGGL((gat_aggregate_kernel<1, F, 64, float>), dim3(N), dim3(64), 0, stream, g2b,
                       as2, ad2, row_start, csr_src, b2, out, N);
}